// Round 7
// baseline (2707.041 us; speedup 1.0000x reference)
//
#include <hip/hip_runtime.h>
#include <hip/hip_fp16.h>
#include <stdint.h>

#define SEQ 512
#define HIDN 512

typedef _Float16 h2_t __attribute__((ext_vector_type(2)));
typedef _Float16 h8_t __attribute__((ext_vector_type(8)));
typedef float f4_t __attribute__((ext_vector_type(4)));

__device__ __forceinline__ float fdot2f(uint32_t a, uint32_t b, float c) {
#if __has_builtin(__builtin_amdgcn_fdot2)
  return __builtin_amdgcn_fdot2(__builtin_bit_cast(h2_t, a),
                                __builtin_bit_cast(h2_t, b), c, false);
#else
  h2_t ah = __builtin_bit_cast(h2_t, a);
  h2_t bh = __builtin_bit_cast(h2_t, b);
  return c + (float)ah.x * (float)bh.x + (float)ah.y * (float)bh.y;
#endif
}

// ---------------- fp32 -> fp16 convert (contiguous) ----------------
__global__ void k_cvt(const float4* __restrict__ src, __half2* __restrict__ dst, int n4) {
  int i = blockIdx.x * blockDim.x + threadIdx.x;
  if (i < n4) {
    float4 v = src[i];
    dst[2 * i]     = __floats2half2_rn(v.x, v.y);
    dst[2 * i + 1] = __floats2half2_rn(v.z, v.w);
  }
}

// ---------------- transpose + convert: dst[c][r] = (half)src[r][c] ----------------
__global__ void k_transpose_cvt(const float* __restrict__ src, __half* __restrict__ dst,
                                int R, int C) {
  __shared__ float tile[32][33];
  int tx = threadIdx.x, ty = threadIdx.y;
  int c0 = blockIdx.x * 32, r0 = blockIdx.y * 32;
#pragma unroll
  for (int i = 0; i < 4; ++i)
    tile[ty + i * 8][tx] = src[(size_t)(r0 + ty + i * 8) * C + c0 + tx];
  __syncthreads();
#pragma unroll
  for (int i = 0; i < 4; ++i)
    dst[(size_t)(c0 + ty + i * 8) * R + r0 + tx] = __float2half(tile[tx][ty + i * 8]);
}

// ---------------- Wh repack: chunk-major f16 for k_rnn ----------------
// k_rnn thread t = (half = t>>9, j = t&511) owns uint4 chunks c = 0..31 of
// column j, where chunk c <-> global chunk g = half*32 + c of WhT row j
// (= Wh[8g..8g+8][j], pairs packed into 4x half2).
// Layout: Wp[c*1024 + t] -> every wave-access of a fixed c is 64 consecutive
// uint4 = 1KB, perfectly coalesced (global loads AND the LDS-copy init).
__global__ void k_wprep(const float* __restrict__ W, uint4* __restrict__ dst) {
  int idx = blockIdx.x * 256 + threadIdx.x;   // 32768 threads
  int c = idx >> 10;
  int r = idx & 1023;
  int half = r >> 9;
  int j = r & 511;
  int g = half * 32 + c;
  const float* src = W + (size_t)(512 + g * 8) * 512 + j;  // Wh rows of W (EMB+HID,HID)
  uint32_t u0 = __builtin_bit_cast(uint32_t, __floats2half2_rn(src[0],    src[512]));
  uint32_t u1 = __builtin_bit_cast(uint32_t, __floats2half2_rn(src[1024], src[1536]));
  uint32_t u2 = __builtin_bit_cast(uint32_t, __floats2half2_rn(src[2048], src[2560]));
  uint32_t u3 = __builtin_bit_cast(uint32_t, __floats2half2_rn(src[3072], src[3584]));
  uint4 v; v.x = u0; v.y = u1; v.z = u2; v.w = u3;
  dst[idx] = v;
}

// ---------------- f16 MFMA GEMM: C(MxN,f32) = A(MxK,f16) * Bt(NxK,f16)^T + bias ----------------
__global__ __launch_bounds__(256, 2) void k_gemm(
    const __half* __restrict__ A, const __half* __restrict__ Bt,
    const float* __restrict__ bias, float* __restrict__ C,
    int M, int N, int K) {
  __shared__ __align__(16) __half As[128 * 32];
  __shared__ __align__(16) __half Bs[128 * 32];
  const int tid = threadIdx.x;
  const int m0 = blockIdx.x * 128;
  const int n0 = blockIdx.y * 128;
  const int w = tid >> 6;
  const int lane = tid & 63;
  const int wm = (w >> 1) * 64;
  const int wn = (w & 1) * 64;
  const int fr = lane & 15;
  const int q = lane >> 4;
  const int lr = tid >> 2;
  const int lc = tid & 3;
  f4_t acc[4][4];
#pragma unroll
  for (int i = 0; i < 4; ++i)
#pragma unroll
    for (int jj = 0; jj < 4; ++jj) acc[i][jj] = (f4_t)(0.f);

  for (int kk = 0; kk < K; kk += 32) {
    *(uint4*)&As[lr * 32 + lc * 8]        = *(const uint4*)&A[(size_t)(m0 + lr) * K + kk + lc * 8];
    *(uint4*)&As[(64 + lr) * 32 + lc * 8] = *(const uint4*)&A[(size_t)(m0 + 64 + lr) * K + kk + lc * 8];
    *(uint4*)&Bs[lr * 32 + lc * 8]        = *(const uint4*)&Bt[(size_t)(n0 + lr) * K + kk + lc * 8];
    *(uint4*)&Bs[(64 + lr) * 32 + lc * 8] = *(const uint4*)&Bt[(size_t)(n0 + 64 + lr) * K + kk + lc * 8];
    __syncthreads();
    h8_t af[4], bf[4];
#pragma unroll
    for (int i = 0; i < 4; ++i) {
      af[i] = *(const h8_t*)&As[(wm + i * 16 + fr) * 32 + q * 8];
      bf[i] = *(const h8_t*)&Bs[(wn + i * 16 + fr) * 32 + q * 8];
    }
#pragma unroll
    for (int i = 0; i < 4; ++i)
#pragma unroll
      for (int jj = 0; jj < 4; ++jj)
        acc[i][jj] = __builtin_amdgcn_mfma_f32_16x16x32_f16(af[i], bf[jj], acc[i][jj], 0, 0, 0);
    __syncthreads();
  }
#pragma unroll
  for (int i = 0; i < 4; ++i) {
    const int row0 = m0 + wm + i * 16 + q * 4;
#pragma unroll
    for (int jj = 0; jj < 4; ++jj) {
      const int col = n0 + wn + jj * 16 + fr;
      const float bv = bias[col];
#pragma unroll
      for (int r = 0; r < 4; ++r)
        C[(size_t)(row0 + r) * N + col] = acc[i][jj][r] + bv;
    }
  }
}

// ---------------- serial recurrence: 64 blocks x 1024 threads ----------------
// Calibrated model (R0/R6 reconciliation): per-CU VMEM ~90 B/cyc (L2-hit
// stream) -> 182 cyc per re-streamed chunk/step; per-lane ds_read_b128
// ~12 cyc/wave-inst -> 192 cyc per LDS chunk/step; uniform LDS/global reads
// ~free; v_accvgpr_read has issue+wait-state tax (~70-150 cyc/chunk) — AGPRs
// are cheap to HOLD, costly to READ on the VALU path.
// R7 balance of the 32 chunks/thread across three pipes, h evicted from LDS:
//   chunks  0..13  AGPR  (56 regs; 56 reads/step; VALU ~1700-2200)
//   chunks 14..22  LDS   (147KB array; LDS pipe ~1930 incl psum)
//   chunks 23..31  L2    (144KB/step; VMEM ~1840 incl h+a loads)
// h lives in GLOBAL (hx, 1KB, L1-hot): producer and consumers are the same
// CU; __syncthreads drains vmcnt before s_barrier, so same-CU L1 reads after
// the barrier are coherent. LDS pipe no longer carries the h broadcast.
// No sched_barriers (R3-R5 lesson: they serialize the step).
__global__ __launch_bounds__(1024) void k_rnn(
    const uint4* __restrict__ Wp_f, const uint4* __restrict__ Wp_b,
    const float* __restrict__ A_f, const float* __restrict__ A_b,
    __half* __restrict__ bi, __half* __restrict__ hx) {
  __shared__ __align__(16) uint4 ldsw4[9 * 1024];  // 147456 B: chunks 14..22
  __shared__ float psum[HIDN];                     // 2 KB half1 partials
  const int t = threadIdx.x;
  const int j = t & 511;
  const int half = t >> 9;                         // waves 0-7: half0, 8-15: half1
  const int d = blockIdx.x & 1;
  const int b = blockIdx.x >> 1;
  const uint4* Wp = d ? Wp_b : Wp_f;
  const float* A = (d ? A_b : A_f) + (size_t)b * SEQ * HIDN;
  __half* bip = bi + (size_t)b * SEQ * 1024 + d * HIDN + j;
  __half* hxg = hx + (size_t)blockIdx.x * 1024;    // [parity][512] per block
  const uint4* Wg = Wp + 23 * 1024;                // global-streamed chunks

  // --- init: chunks 0..13 -> AGPRs (forced via "a" constraints) ---
  uint32_t ag[56];
#pragma unroll
  for (int i = 0; i < 14; ++i) {
    uint4 w = Wp[i * 1024 + t];
    asm volatile("v_accvgpr_write_b32 %0, %1" : "=a"(ag[4 * i + 0]) : "v"(w.x));
    asm volatile("v_accvgpr_write_b32 %0, %1" : "=a"(ag[4 * i + 1]) : "v"(w.y));
    asm volatile("v_accvgpr_write_b32 %0, %1" : "=a"(ag[4 * i + 2]) : "v"(w.z));
    asm volatile("v_accvgpr_write_b32 %0, %1" : "=a"(ag[4 * i + 3]) : "v"(w.w));
  }
  // --- init: chunks 14..22 -> LDS (coalesced b128 copy) ---
#pragma unroll
  for (int p = 0; p < 9; ++p) ldsw4[p * 1024 + t] = Wp[(14 + p) * 1024 + t];
  if (half == 0) hxg[j] = __float2half(0.f);       // h_0 = 0, parity 0
  __syncthreads();

  const int tstep = d ? -1 : 1;
  int tt = d ? (SEQ - 1) : 0;
  float a_next = (half == 0) ? A[(size_t)tt * HIDN + j] : 0.f;
  int cur = 0;
#pragma unroll 1
  for (int s = 0; s < SEQ; ++s) {
    // wave-uniform global reads of h (L1-hot, 1 request per wave per chunk)
    const uint4* hp = (const uint4*)(hxg + cur * HIDN) + half * 32;
    float c0 = 0.f, c1 = 0.f, c2 = 0.f, c3 = 0.f;

    // chunks 0..13: AGPR-resident (reads grouped per chunk; fdot2 of chunk i
    // schedules under the volatile reads of chunk i+1)
#pragma unroll
    for (int i = 0; i < 14; ++i) {
      uint32_t wx, wy, wz, ww;
      asm volatile("v_accvgpr_read_b32 %0, %1" : "=v"(wx) : "a"(ag[4 * i + 0]));
      asm volatile("v_accvgpr_read_b32 %0, %1" : "=v"(wy) : "a"(ag[4 * i + 1]));
      asm volatile("v_accvgpr_read_b32 %0, %1" : "=v"(wz) : "a"(ag[4 * i + 2]));
      asm volatile("v_accvgpr_read_b32 %0, %1" : "=v"(ww) : "a"(ag[4 * i + 3]));
      uint4 hv = hp[i];
      c0 = fdot2f(hv.x, wx, c0);
      c1 = fdot2f(hv.y, wy, c1);
      c2 = fdot2f(hv.z, wz, c2);
      c3 = fdot2f(hv.w, ww, c3);
    }
    // chunks 14..22: LDS-resident (per-lane b128, ~12 cyc/wave-inst)
#pragma unroll
    for (int p = 0; p < 9; ++p) {
      uint4 hv = hp[14 + p];
      uint4 lw = ldsw4[p * 1024 + t];
      c0 = fdot2f(hv.x, lw.x, c0);
      c1 = fdot2f(hv.y, lw.y, c1);
      c2 = fdot2f(hv.z, lw.z, c2);
      c3 = fdot2f(hv.w, lw.w, c3);
    }
    // chunks 23..31: L2 re-stream (vmem pipe, latency hidden by TLP)
#pragma unroll
    for (int i = 0; i < 9; ++i) {
      uint4 w = Wg[i * 1024 + t];
      uint4 hv = hp[23 + i];
      c0 = fdot2f(hv.x, w.x, c0);
      c1 = fdot2f(hv.y, w.y, c1);
      c2 = fdot2f(hv.z, w.z, c2);
      c3 = fdot2f(hv.w, w.w, c3);
    }

    float part = (c0 + c1) + (c2 + c3);
    if (half) psum[j] = part;                      // wave-uniform branch
    __syncthreads();
    if (half == 0) {
      float a_use = a_next;
      int tn = tt + tstep;
      tn = tn < 0 ? 0 : (tn > SEQ - 1 ? SEQ - 1 : tn);
      a_next = A[(size_t)tn * HIDN + j];           // prefetch next step's a-term
      float p = part + psum[j] + a_use;
      float ap = fabsf(p);
      float e = __expf(2.f * ap);
      float th = 1.f - 2.f * __builtin_amdgcn_rcpf(e + 1.f);  // tanh(|p|)
      float h = copysignf(th, p);
      __half hh = __float2half(h);
      hxg[(cur ^ 1) * HIDN + j] = hh;              // publish h (coalesced 1KB)
      bip[(size_t)tt * 1024] = hh;                 // output row
    }
    __syncthreads();                               // drains vmcnt -> h visible
    cur ^= 1;
    tt += tstep;
  }
}

extern "C" void kernel_launch(void* const* d_in, const int* in_sizes, int n_in,
                              void* d_out, int out_size, void* d_ws, size_t ws_size,
                              hipStream_t stream) {
  const float* input_seq = (const float*)d_in[0];  // (32,512,512)
  const float* W_f = (const float*)d_in[1];        // (1024,512)
  const float* b_f = (const float*)d_in[2];
  const float* W_b = (const float*)d_in[3];
  const float* b_b = (const float*)d_in[4];
  const float* W_o = (const float*)d_in[5];        // (1024,512)
  const float* b_o = (const float*)d_in[6];
  float* out = (float*)d_out;

  char* ws = (char*)d_ws;
  __half* Xh    = (__half*)(ws);                    // 16 MB  (16384x512 f16)
  float*  A_f   = (float*)(ws + 16777216);          // 32 MB
  float*  A_b   = (float*)(ws + 50331648);          // 32 MB
  __half* bi    = (__half*)(ws + 83886080);         // 32 MB  (16384x1024 f16)
  __half* WxT_f = (__half*)(ws + 117440512);        // 512 KB
  __half* WxT_b = (__half*)(ws + 117964800);
  uint4*  Wp_f  = (uint4*)(ws + 118489088);         // 512 KB chunk-major Wh_f
  uint4*  Wp_b  = (uint4*)(ws + 119013376);         // 512 KB chunk-major Wh_b
  __half* WoT   = (__half*)(ws + 119537664);        // 1 MB
  __half* hx    = (__half*)(ws + 120586240);        // 128 KB: 64 blocks x 2 x 512 f16

  k_cvt<<<8192, 256, 0, stream>>>((const float4*)input_seq, (__half2*)Xh, 2097152);
  dim3 tb(32, 8);
  k_transpose_cvt<<<dim3(16, 16), tb, 0, stream>>>(W_f, WxT_f, 512, 512);
  k_transpose_cvt<<<dim3(16, 16), tb, 0, stream>>>(W_b, WxT_b, 512, 512);
  k_transpose_cvt<<<dim3(16, 32), tb, 0, stream>>>(W_o, WoT, 1024, 512);
  k_wprep<<<128, 256, 0, stream>>>(W_f, Wp_f);
  k_wprep<<<128, 256, 0, stream>>>(W_b, Wp_b);

  k_gemm<<<dim3(128, 4), 256, 0, stream>>>(Xh, WxT_f, b_f, A_f, 16384, 512, 512);
  k_gemm<<<dim3(128, 4), 256, 0, stream>>>(Xh, WxT_b, b_b, A_b, 16384, 512, 512);

  k_rnn<<<64, 1024, 0, stream>>>(Wp_f, Wp_b, A_f, A_b, bi, hx);

  k_gemm<<<dim3(128, 4), 256, 0, stream>>>(bi, WoT, b_o, out, 16384, 512, 1024);
}

// Round 8
// 1086.088 us; speedup vs baseline: 2.4925x; 2.4925x over previous
//
#include <hip/hip_runtime.h>
#include <hip/hip_fp16.h>
#include <stdint.h>

#define SEQ 512
#define HIDN 512

typedef _Float16 h2_t __attribute__((ext_vector_type(2)));
typedef _Float16 h8_t __attribute__((ext_vector_type(8)));
typedef float f4_t __attribute__((ext_vector_type(4)));

__device__ __forceinline__ float fdot2f(uint32_t a, uint32_t b, float c) {
#if __has_builtin(__builtin_amdgcn_fdot2)
  return __builtin_amdgcn_fdot2(__builtin_bit_cast(h2_t, a),
                                __builtin_bit_cast(h2_t, b), c, false);
#else
  h2_t ah = __builtin_bit_cast(h2_t, a);
  h2_t bh = __builtin_bit_cast(h2_t, b);
  return c + (float)ah.x * (float)bh.x + (float)ah.y * (float)bh.y;
#endif
}

// ---------------- fp32 -> fp16 convert (contiguous) ----------------
__global__ void k_cvt(const float4* __restrict__ src, __half2* __restrict__ dst, int n4) {
  int i = blockIdx.x * blockDim.x + threadIdx.x;
  if (i < n4) {
    float4 v = src[i];
    dst[2 * i]     = __floats2half2_rn(v.x, v.y);
    dst[2 * i + 1] = __floats2half2_rn(v.z, v.w);
  }
}

// ---------------- transpose + convert: dst[c][r] = (half)src[r][c] ----------------
__global__ void k_transpose_cvt(const float* __restrict__ src, __half* __restrict__ dst,
                                int R, int C) {
  __shared__ float tile[32][33];
  int tx = threadIdx.x, ty = threadIdx.y;
  int c0 = blockIdx.x * 32, r0 = blockIdx.y * 32;
#pragma unroll
  for (int i = 0; i < 4; ++i)
    tile[ty + i * 8][tx] = src[(size_t)(r0 + ty + i * 8) * C + c0 + tx];
  __syncthreads();
#pragma unroll
  for (int i = 0; i < 4; ++i)
    dst[(size_t)(c0 + ty + i * 8) * R + r0 + tx] = __float2half(tile[tx][ty + i * 8]);
}

// ---------------- Wh repack: chunk-major f16 for k_rnn ----------------
// k_rnn thread t = (half = t>>9, j = t&511) owns uint4 chunks c = 0..31 of
// column j, where chunk c <-> global chunk g = half*32 + c of WhT row j
// (= Wh[8g..8g+8][j], pairs packed into 4x half2).
// Layout: Wp[c*1024 + t] -> every wave-access of a fixed c is 64 consecutive
// uint4 = 1KB, perfectly coalesced (global streams AND the LDS-copy init).
__global__ void k_wprep(const float* __restrict__ W, uint4* __restrict__ dst) {
  int idx = blockIdx.x * 256 + threadIdx.x;   // 32768 threads
  int c = idx >> 10;
  int r = idx & 1023;
  int half = r >> 9;
  int j = r & 511;
  int g = half * 32 + c;
  const float* src = W + (size_t)(512 + g * 8) * 512 + j;  // Wh rows of W (EMB+HID,HID)
  uint32_t u0 = __builtin_bit_cast(uint32_t, __floats2half2_rn(src[0],    src[512]));
  uint32_t u1 = __builtin_bit_cast(uint32_t, __floats2half2_rn(src[1024], src[1536]));
  uint32_t u2 = __builtin_bit_cast(uint32_t, __floats2half2_rn(src[2048], src[2560]));
  uint32_t u3 = __builtin_bit_cast(uint32_t, __floats2half2_rn(src[3072], src[3584]));
  uint4 v; v.x = u0; v.y = u1; v.z = u2; v.w = u3;
  dst[idx] = v;
}

// ---------------- f16 MFMA GEMM: C(MxN,f32) = A(MxK,f16) * Bt(NxK,f16)^T + bias ----------------
__global__ __launch_bounds__(256, 2) void k_gemm(
    const __half* __restrict__ A, const __half* __restrict__ Bt,
    const float* __restrict__ bias, float* __restrict__ C,
    int M, int N, int K) {
  __shared__ __align__(16) __half As[128 * 32];
  __shared__ __align__(16) __half Bs[128 * 32];
  const int tid = threadIdx.x;
  const int m0 = blockIdx.x * 128;
  const int n0 = blockIdx.y * 128;
  const int w = tid >> 6;
  const int lane = tid & 63;
  const int wm = (w >> 1) * 64;
  const int wn = (w & 1) * 64;
  const int fr = lane & 15;
  const int q = lane >> 4;
  const int lr = tid >> 2;
  const int lc = tid & 3;
  f4_t acc[4][4];
#pragma unroll
  for (int i = 0; i < 4; ++i)
#pragma unroll
    for (int jj = 0; jj < 4; ++jj) acc[i][jj] = (f4_t)(0.f);

  for (int kk = 0; kk < K; kk += 32) {
    *(uint4*)&As[lr * 32 + lc * 8]        = *(const uint4*)&A[(size_t)(m0 + lr) * K + kk + lc * 8];
    *(uint4*)&As[(64 + lr) * 32 + lc * 8] = *(const uint4*)&A[(size_t)(m0 + 64 + lr) * K + kk + lc * 8];
    *(uint4*)&Bs[lr * 32 + lc * 8]        = *(const uint4*)&Bt[(size_t)(n0 + lr) * K + kk + lc * 8];
    *(uint4*)&Bs[(64 + lr) * 32 + lc * 8] = *(const uint4*)&Bt[(size_t)(n0 + 64 + lr) * K + kk + lc * 8];
    __syncthreads();
    h8_t af[4], bf[4];
#pragma unroll
    for (int i = 0; i < 4; ++i) {
      af[i] = *(const h8_t*)&As[(wm + i * 16 + fr) * 32 + q * 8];
      bf[i] = *(const h8_t*)&Bs[(wn + i * 16 + fr) * 32 + q * 8];
    }
#pragma unroll
    for (int i = 0; i < 4; ++i)
#pragma unroll
      for (int jj = 0; jj < 4; ++jj)
        acc[i][jj] = __builtin_amdgcn_mfma_f32_16x16x32_f16(af[i], bf[jj], acc[i][jj], 0, 0, 0);
    __syncthreads();
  }
#pragma unroll
  for (int i = 0; i < 4; ++i) {
    const int row0 = m0 + wm + i * 16 + q * 4;
#pragma unroll
    for (int jj = 0; jj < 4; ++jj) {
      const int col = n0 + wn + jj * 16 + fr;
      const float bv = bias[col];
#pragma unroll
      for (int r = 0; r < 4; ++r)
        C[(size_t)(row0 + r) * N + col] = acc[i][jj][r] + bv;
    }
  }
}

// ---------------- serial recurrence: 64 blocks x 1024 threads ----------------
// Ladder reconciliation (cyc/step/CU): R0=4030 (23 row-pattern L2 streams:
// 1KB inter-lane stride, ~368KB/step), R6=5485 (AGPR read tax ~250cyc/chunk:
// RAW wait-states the volatile asm order can't hide), R7=12100 (h in global:
// uniform VMEM loads are NOT broadcast — 200-400cyc each on the serial path).
// R8 combines only the proven-good parts:
//   h in LDS        (uniform ds_read_b128 broadcast, ~2 cyc/wave-inst)
//   chunks  0..7    VGPR wv[8] = 32 regs — fits the 64-reg budget the
//                   allocator actually enforces (R0 asked 92, got remat);
//                   benign failure mode: remat = more coalesced streaming
//   chunks  8..16   LDS tile (147KB written once; ~192 cyc/chunk/step)
//   chunks 17..31   L2 stream, chunk-major COALESCED (1KB/wave-inst;
//                   ~128 B/cyc/CU -> ~1920 cyc/step, overlaps LDS+VALU)
// No AGPRs, no sched_barriers (R3-R5: they serialize), 2 barriers/step.
// Pipe model: LDS 2850 | VMEM 2220 | VALU ~2100 -> step ~3000 cyc.
__global__ __launch_bounds__(1024) void k_rnn(
    const uint4* __restrict__ Wp_f, const uint4* __restrict__ Wp_b,
    const float* __restrict__ A_f, const float* __restrict__ A_b,
    __half* __restrict__ bi) {
  __shared__ __align__(16) uint4 ldsw4[9 * 1024];  // 147456 B: chunks 8..16
  __shared__ __align__(16) __half hbuf[2][HIDN];   // 2 KB double-buffered h
  __shared__ float psum[HIDN];                     // 2 KB half1 partials
  const int t = threadIdx.x;
  const int j = t & 511;
  const int half = t >> 9;                         // waves 0-7: half0, 8-15: half1
  const int d = blockIdx.x & 1;
  const int b = blockIdx.x >> 1;
  const uint4* Wp = d ? Wp_b : Wp_f;
  const float* A = (d ? A_b : A_f) + (size_t)b * SEQ * HIDN;
  __half* bip = bi + (size_t)b * SEQ * 1024 + d * HIDN + j;
  const uint4* Wg = Wp + 17 * 1024;                // streamed chunks 17..31

  uint4 wv[8];                                     // resident: 32 VGPRs
#pragma unroll
  for (int i = 0; i < 8; ++i) wv[i] = Wp[i * 1024 + t];
#pragma unroll
  for (int p = 0; p < 9; ++p) ldsw4[p * 1024 + t] = Wp[(8 + p) * 1024 + t];
  if (half == 0) hbuf[0][j] = __float2half(0.f);
  __syncthreads();

  const int tstep = d ? -1 : 1;
  int tt = d ? (SEQ - 1) : 0;
  float a_next = (half == 0) ? A[(size_t)tt * HIDN + j] : 0.f;
  int cur = 0;
#pragma unroll 1
  for (int s = 0; s < SEQ; ++s) {
    const uint4* hp = (const uint4*)hbuf[cur] + half * 32;  // wave-uniform addr
    float c0 = 0.f, c1 = 0.f, c2 = 0.f, c3 = 0.f;

    // chunks 17..31: coalesced L2 stream — source-first so loads issue early
    // and the resident/LDS fdot2 work below fills their latency.
#pragma unroll
    for (int i = 0; i < 15; ++i) {
      uint4 w = Wg[i * 1024 + t];
      uint4 hv = hp[17 + i];
      c0 = fdot2f(hv.x, w.x, c0);
      c1 = fdot2f(hv.y, w.y, c1);
      c2 = fdot2f(hv.z, w.z, c2);
      c3 = fdot2f(hv.w, w.w, c3);
    }
    // chunks 0..7: VGPR-resident
#pragma unroll
    for (int i = 0; i < 8; ++i) {
      uint4 hv = hp[i];
      c0 = fdot2f(hv.x, wv[i].x, c0);
      c1 = fdot2f(hv.y, wv[i].y, c1);
      c2 = fdot2f(hv.z, wv[i].z, c2);
      c3 = fdot2f(hv.w, wv[i].w, c3);
    }
    // chunks 8..16: LDS-resident (per-lane b128)
#pragma unroll
    for (int p = 0; p < 9; ++p) {
      uint4 hv = hp[8 + p];
      uint4 lw = ldsw4[p * 1024 + t];
      c0 = fdot2f(hv.x, lw.x, c0);
      c1 = fdot2f(hv.y, lw.y, c1);
      c2 = fdot2f(hv.z, lw.z, c2);
      c3 = fdot2f(hv.w, lw.w, c3);
    }

    float part = (c0 + c1) + (c2 + c3);
    if (half) psum[j] = part;                      // wave-uniform branch
    __syncthreads();
    if (half == 0) {
      float a_use = a_next;
      int tn = tt + tstep;
      tn = tn < 0 ? 0 : (tn > SEQ - 1 ? SEQ - 1 : tn);
      a_next = A[(size_t)tn * HIDN + j];           // prefetch next step's a-term
      float p = part + psum[j] + a_use;
      float ap = fabsf(p);
      float e = __expf(2.f * ap);
      float th = 1.f - 2.f * __builtin_amdgcn_rcpf(e + 1.f);  // tanh(|p|)
      float h = copysignf(th, p);
      __half hh = __float2half(h);
      hbuf[cur ^ 1][j] = hh;
      bip[(size_t)tt * 1024] = hh;
    }
    __syncthreads();
    cur ^= 1;
    tt += tstep;
  }
}

extern "C" void kernel_launch(void* const* d_in, const int* in_sizes, int n_in,
                              void* d_out, int out_size, void* d_ws, size_t ws_size,
                              hipStream_t stream) {
  const float* input_seq = (const float*)d_in[0];  // (32,512,512)
  const float* W_f = (const float*)d_in[1];        // (1024,512)
  const float* b_f = (const float*)d_in[2];
  const float* W_b = (const float*)d_in[3];
  const float* b_b = (const float*)d_in[4];
  const float* W_o = (const float*)d_in[5];        // (1024,512)
  const float* b_o = (const float*)d_in[6];
  float* out = (float*)d_out;

  char* ws = (char*)d_ws;
  __half* Xh    = (__half*)(ws);                    // 16 MB  (16384x512 f16)
  float*  A_f   = (float*)(ws + 16777216);          // 32 MB
  float*  A_b   = (float*)(ws + 50331648);          // 32 MB
  __half* bi    = (__half*)(ws + 83886080);         // 32 MB  (16384x1024 f16)
  __half* WxT_f = (__half*)(ws + 117440512);        // 512 KB
  __half* WxT_b = (__half*)(ws + 117964800);
  uint4*  Wp_f  = (uint4*)(ws + 118489088);         // 512 KB chunk-major Wh_f
  uint4*  Wp_b  = (uint4*)(ws + 119013376);         // 512 KB chunk-major Wh_b
  __half* WoT   = (__half*)(ws + 119537664);        // 1 MB

  k_cvt<<<8192, 256, 0, stream>>>((const float4*)input_seq, (__half2*)Xh, 2097152);
  dim3 tb(32, 8);
  k_transpose_cvt<<<dim3(16, 16), tb, 0, stream>>>(W_f, WxT_f, 512, 512);
  k_transpose_cvt<<<dim3(16, 16), tb, 0, stream>>>(W_b, WxT_b, 512, 512);
  k_transpose_cvt<<<dim3(16, 32), tb, 0, stream>>>(W_o, WoT, 1024, 512);
  k_wprep<<<128, 256, 0, stream>>>(W_f, Wp_f);
  k_wprep<<<128, 256, 0, stream>>>(W_b, Wp_b);

  k_gemm<<<dim3(128, 4), 256, 0, stream>>>(Xh, WxT_f, b_f, A_f, 16384, 512, 512);
  k_gemm<<<dim3(128, 4), 256, 0, stream>>>(Xh, WxT_b, b_b, A_b, 16384, 512, 512);

  k_rnn<<<64, 1024, 0, stream>>>(Wp_f, Wp_b, A_f, A_b, bi);

  k_gemm<<<dim3(128, 4), 256, 0, stream>>>(bi, WoT, b_o, out, 16384, 512, 1024);
}